// Round 4
// baseline (1832.426 us; speedup 1.0000x reference)
//
#include <hip/hip_runtime.h>
#include <hip/hip_bf16.h>
#include <stdint.h>

// ---------- types ----------
using f32x4  = __attribute__((ext_vector_type(4))) float;
using bf16x8 = __attribute__((ext_vector_type(8))) __bf16;
using short8 = __attribute__((ext_vector_type(8))) short;

__device__ __forceinline__ short f2b(float f) {
    unsigned u = __builtin_bit_cast(unsigned, f);
    unsigned r = (u + 0x7fff + ((u >> 16) & 1)) >> 16;   // RNE
    return (short)r;
}
__device__ __forceinline__ float b2f(short s) {
    unsigned u = ((unsigned)(unsigned short)s) << 16;
    return __builtin_bit_cast(float, u);
}
__device__ __forceinline__ float sigf(float x) {
    return __builtin_amdgcn_rcpf(1.f + __expf(-x));
}
__device__ __forceinline__ float tanhf_fast(float x) {
    x = fminf(fmaxf(x, -15.f), 15.f);
    return 2.f * __builtin_amdgcn_rcpf(1.f + __expf(-2.f * x)) - 1.f;
}

// ---------- laneGate ----------
__global__ __launch_bounds__(256) void lanec_k(const float* lane, const float* W1, const float* b1,
                                               const float* W2, const float* b2, float* laneC) {
    int s = blockIdx.x * 256 + threadIdx.x;
    float v = lane[s];
    float acc = b2[0];
    #pragma unroll
    for (int k = 0; k < 32; ++k) {
        float t = fmaxf(v * W1[k] + b1[k], 0.f);
        acc += t * W2[k];
    }
    laneC[s] = 1.f / (1.f + __expf(-acc));
}

// ---------- weight packing ----------
// pW2: MFMA-frag-major [12 kc][64 fg][64 lane][8 e], fg = w*8 + f, f = g*2 + u.
// (w,u,lj) -> j = 32w + 16u + lj; gate g; combined row n = g*256 + j.
// k = kc*32 + lk*8 + e (k<128 -> Wih col, else Whh col k-128).
__global__ __launch_bounds__(256) void pack_k(const float* Wih, const float* Whh, const float* bih,
                                              const float* bhh, const float* oW, const float* fW1,
                                              const float* fW2, const float* eW2,
                                              short* pW2, float* biasP,
                                              short* oWp, short* fW1p, short* fW2p, short* eW2p) {
    int i = blockIdx.x * 256 + threadIdx.x;
    if (i < 393216) {
        int e = i & 7, l = (i >> 3) & 63, fg = (i >> 9) & 63, kc = i >> 15;
        int w = fg >> 3, f = fg & 7;
        int lj = l & 15, lk = l >> 4;
        int g = f >> 1, u = f & 1;
        int j = 32 * w + 16 * u + lj;
        int n = g * 256 + j;
        int k = kc * 32 + lk * 8 + e;
        pW2[i] = f2b(k < 128 ? Wih[n * 128 + k] : Whh[n * 256 + (k - 128)]);
        return;
    }
    i -= 393216;
    if (i < 1024) {                                    // biasP[w*128 + f*16 + lj]
        int lj = i & 15, f = (i >> 4) & 7, w = i >> 7;
        int g = f >> 1, u = f & 1;
        int j = 32 * w + 16 * u + lj;
        int n = g * 256 + j;
        biasP[i] = bih[n] + bhh[n];
        return;
    }
    i -= 1024;
    if (i < 32768) { oWp[i] = f2b(oW[i]); return; }    // [128][256]
    i -= 32768;
    if (i < 32768) { fW1p[i] = f2b(fW1[i]); return; }  // [256][128]
    i -= 32768;
    if (i < 32768) {                                   // fW2p [128(pad)][256]
        int n = i / 256;
        fW2p[i] = (n < 64) ? f2b(fW2[i]) : (short)0;
        return;
    }
    i -= 32768;
    if (i < 8192) { eW2p[i] = f2b(eW2[i]); return; }   // [128][64]
}

// ---------- embedding layer 1 ----------
__global__ __launch_bounds__(256) void embed1_k(const float* inp, const float* laneC,
                                                const float* eW1, const float* eb1, short* h1) {
    int g = threadIdx.x >> 6, j = threadIdx.x & 63;
    int t = blockIdx.x >> 10;
    int s = ((blockIdx.x & 1023) << 2) + g;
    float lc = laneC[s];
    size_t rin = ((size_t)s * 64 + t) * 3;
    float x0 = inp[rin] * lc, x1 = inp[rin + 1] * lc, x2 = inp[rin + 2] * lc;
    float h = fmaxf(eW1[j * 3] * x0 + eW1[j * 3 + 1] * x1 + eW1[j * 3 + 2] * x2 + eb1[j], 0.f);
    h1[((size_t)t * 4096 + s) * 64 + j] = f2b(h);
}

// ---------- generic bf16 MFMA GEMM (embed layer2 + head) ----------
__global__ __launch_bounds__(256) void gemm_k(const short* A1, int K1, const short* A2, int K2,
                                              const short* B, int Kt, const float* bias,
                                              float* outF, short* outB, int Nstore, int Nreal,
                                              int relu) {
    __shared__ alignas(16) short As[128 * 32];
    __shared__ alignas(16) short Bs[128 * 32];
    int tid = threadIdx.x;
    int wave = tid >> 6, lane = tid & 63;
    int m0 = blockIdx.x * 128, n0 = blockIdx.y * 128;

    f32x4 acc[4][4];
    #pragma unroll
    for (int i = 0; i < 4; ++i)
        #pragma unroll
        for (int j = 0; j < 4; ++j) acc[i][j] = (f32x4){0.f, 0.f, 0.f, 0.f};

    const int lr = lane & 15, lk8 = (lane >> 4) * 8;
    const int am = (wave & 1) * 64, bn = (wave >> 1) * 64;
    const int row = tid >> 2, c8 = (tid & 3) * 8;
    int nK = Kt / 32;

    for (int kt = 0; kt < nK; ++kt) {
        int kk = kt * 32;
        const short* Asrc; int astr, acol;
        if (kk < K1) { Asrc = A1; astr = K1; acol = kk; }
        else         { Asrc = A2; astr = K2; acol = kk - K1; }
        short8 a0 = *(const short8*)(Asrc + (size_t)(m0 + row) * astr + acol + c8);
        short8 a1 = *(const short8*)(Asrc + (size_t)(m0 + 64 + row) * astr + acol + c8);
        short8 b0 = *(const short8*)(B + (size_t)(n0 + row) * Kt + kk + c8);
        short8 b1 = *(const short8*)(B + (size_t)(n0 + 64 + row) * Kt + kk + c8);
        __syncthreads();
        *(short8*)&As[tid * 8] = a0;
        *(short8*)&As[(tid + 256) * 8] = a1;
        *(short8*)&Bs[tid * 8] = b0;
        *(short8*)&Bs[(tid + 256) * 8] = b1;
        __syncthreads();
        bf16x8 af[4], bfr[4];
        #pragma unroll
        for (int i = 0; i < 4; ++i) af[i]  = *(const bf16x8*)&As[(am + i * 16 + lr) * 32 + lk8];
        #pragma unroll
        for (int j = 0; j < 4; ++j) bfr[j] = *(const bf16x8*)&Bs[(bn + j * 16 + lr) * 32 + lk8];
        #pragma unroll
        for (int i = 0; i < 4; ++i)
            #pragma unroll
            for (int j = 0; j < 4; ++j)
                acc[i][j] = __builtin_amdgcn_mfma_f32_16x16x32_bf16(af[i], bfr[j], acc[i][j], 0, 0, 0);
    }

    int r0 = m0 + am + (lane >> 4) * 4;
    int c0 = n0 + bn + (lane & 15);
    #pragma unroll
    for (int j = 0; j < 4; ++j) {
        int col = c0 + j * 16;
        if (col >= Nreal) continue;
        float bs = bias[col];
        #pragma unroll
        for (int i = 0; i < 4; ++i) {
            #pragma unroll
            for (int r = 0; r < 4; ++r) {
                int rw = r0 + i * 16 + r;
                float v = acc[i][j][r] + bs;
                if (relu) v = fmaxf(v, 0.f);
                size_t o = (size_t)rw * Nstore + col;
                if (outF) outF[o] = v;
                if (outB) outB[o] = f2b(v);
            }
        }
    }
}

// ---------- persistent fused LSTM v2 ----------
// 256 blocks x 512 threads (8 waves, 2/SIMD, VGPR cap 256). Block owns 16 s-rows.
// Wave w owns N=128 cols = j in [32w,32w+32) x 4 gates. W k-chunks 0..3 (xs half) in
// VGPRs (128 regs); chunks 4..11 (h half) streamed from L2 via global_load_lds into
// a 2x64KB LDS double buffer every step. h kept in frag-major LDS (conflict-free).
__global__ __launch_bounds__(512) void lstm_k(const short* xs, const short* pW2, const float* biasP,
                                              const float* convw, const float* convb,
                                              float* Hd, float* Cd, short* predictb, int staged) {
    __shared__ alignas(16) short Wbuf[2][32768];   // [p][fg][lane][8]
    __shared__ alignas(16) short h_lds[4096];      // [kc' 0..7][lk 0..3][s 0..15][e 0..7]
    __shared__ float hraw[16][258];

    const int tid = threadIdx.x;
    const int w = tid >> 6, l = tid & 63;
    const int lj = l & 15, lk = l >> 4;
    const int s0 = blockIdx.x * 16;

    // W xs-half -> registers: wreg[kc][f], frag-major linear loads
    bf16x8 wreg[4][8];
    #pragma unroll
    for (int kc = 0; kc < 4; ++kc)
        #pragma unroll
        for (int f = 0; f < 8; ++f)
            wreg[kc][f] = *(const bf16x8*)(pW2 + (size_t)((kc * 64 + w * 8 + f) * 64 + l) * 8);
    float biasv[8];
    #pragma unroll
    for (int f = 0; f < 8; ++f) biasv[f] = biasP[w * 128 + f * 16 + lj];
    float creg[2][4] = {{0.f, 0.f, 0.f, 0.f}, {0.f, 0.f, 0.f, 0.f}};
    const float cw0 = convw[0], cw1 = convw[1], cw2 = convw[2], cb = convb[0];

    // zero h state + hraw halos
    for (int i = tid; i < 4096; i += 512) h_lds[i] = 0;
    if (tid < 16) { hraw[tid][0] = 0.f; hraw[tid][257] = 0.f; }
    __syncthreads();

    short* WbufF = &Wbuf[0][0];
    auto issue_chunk = [&](int c, int pp) {
        const short* src = pW2 + (size_t)c * 32768 + tid * 8;
        short* dst = WbufF + pp * 32768 + tid * 8;
        #pragma unroll
        for (int ri = 0; ri < 8; ++ri)
            __builtin_amdgcn_global_load_lds(
                (const __attribute__((address_space(1))) void*)(src + ri * 4096),
                (__attribute__((address_space(3))) void*)(dst + ri * 4096), 16, 0, 0);
    };

    int p = 0;
    issue_chunk(4, 0);

    for (int k = 0; k < 65; ++k) {
        int it = (k <= 48) ? k : k - 1;
        // xs A-frags straight from global (L2-hot): lane holds A[s=lj][k-octet lk]
        const short* xrow = xs + ((size_t)it * 4096 + s0 + lj) * 128 + lk * 8;
        bf16x8 ax0 = *(const bf16x8*)(xrow);
        bf16x8 ax1 = *(const bf16x8*)(xrow + 32);
        bf16x8 ax2 = *(const bf16x8*)(xrow + 64);
        bf16x8 ax3 = *(const bf16x8*)(xrow + 96);

        f32x4 acc[8];
        #pragma unroll
        for (int f = 0; f < 8; ++f) acc[f] = (f32x4){biasv[f], biasv[f], biasv[f], biasv[f]};
        // head: register W chunks 0..3 (xs half) — overlaps chunk-4 stream flight
        #pragma unroll
        for (int f = 0; f < 8; ++f) acc[f] = __builtin_amdgcn_mfma_f32_16x16x32_bf16(ax0, wreg[0][f], acc[f], 0, 0, 0);
        #pragma unroll
        for (int f = 0; f < 8; ++f) acc[f] = __builtin_amdgcn_mfma_f32_16x16x32_bf16(ax1, wreg[1][f], acc[f], 0, 0, 0);
        #pragma unroll
        for (int f = 0; f < 8; ++f) acc[f] = __builtin_amdgcn_mfma_f32_16x16x32_bf16(ax2, wreg[2][f], acc[f], 0, 0, 0);
        #pragma unroll
        for (int f = 0; f < 8; ++f) acc[f] = __builtin_amdgcn_mfma_f32_16x16x32_bf16(ax3, wreg[3][f], acc[f], 0, 0, 0);

        // streamed chunks 4..11 (h half), 1-deep pipeline
        #pragma unroll
        for (int cc = 0; cc < 8; ++cc) {
            asm volatile("s_waitcnt vmcnt(0)" ::: "memory");
            __syncthreads();
            issue_chunk(cc < 7 ? cc + 5 : 4, p ^ 1);    // cc==7 preloads next step's chunk 4
            bf16x8 ah = *(const bf16x8*)&h_lds[((cc * 4 + lk) * 16 + lj) * 8];
            #pragma unroll
            for (int f = 0; f < 8; ++f) {
                bf16x8 wf = *(const bf16x8*)(WbufF + p * 32768 + ((w * 8 + f) * 64 + l) * 8);
                acc[f] = __builtin_amdgcn_mfma_f32_16x16x32_bf16(ah, wf, acc[f], 0, 0, 0);
            }
            p ^= 1;
        }

        // tail: activations + cell update (register-local), hraw -> LDS, C write
        int tslot = (k < 48) ? k : k - 1;
        int doW = (k != 48);
        int pslot = k - 49;
        #pragma unroll
        for (int u = 0; u < 2; ++u) {
            int j = 32 * w + 16 * u + lj;
            #pragma unroll
            for (int r = 0; r < 4; ++r) {
                int s = 4 * lk + r;
                float gi = acc[0 + u][r], gf = acc[2 + u][r];
                float gg = acc[4 + u][r], go = acc[6 + u][r];
                float c = sigf(gf) * creg[u][r] + sigf(gi) * tanhf_fast(gg);
                creg[u][r] = c;
                hraw[s][j + 1] = sigf(go) * tanhf_fast(c);
                if (doW) {
                    size_t o = staged ? ((((size_t)(s0 + s) * 64 + tslot) << 8) + j)
                                      : ((((size_t)(s0 + s) << 8) + j) * 64 + tslot);
                    Cd[o] = c;
                }
            }
        }
        __syncthreads();   // hraw complete (also: all h_lds reads of this step done)

        // conv over hidden dim; h -> frag-major h_lds + global writes
        #pragma unroll
        for (int u = 0; u < 2; ++u) {
            int j = 32 * w + 16 * u + lj;
            int elbase = ((w * 4 + 2 * u + (lj >> 3)) * 16) * 8 + (lj & 7);
            #pragma unroll
            for (int r = 0; r < 4; ++r) {
                int s = 4 * lk + r;
                float h = cw0 * hraw[s][j] + cw1 * hraw[s][j + 1] + cw2 * hraw[s][j + 2] + cb;
                h_lds[elbase + s * 8] = f2b(h);
                if (doW) {
                    size_t o = staged ? ((((size_t)(s0 + s) * 64 + tslot) << 8) + j)
                                      : ((((size_t)(s0 + s) << 8) + j) * 64 + tslot);
                    Hd[o] = h;
                }
                if (pslot >= 0) predictb[(((size_t)(s0 + s) * 16 + pslot) << 8) + j] = f2b(h);
            }
        }
        __syncthreads();   // h_lds ready for next step
    }
}

// ---------- staged [s][t][j] -> output [s][j][t] transpose ----------
__global__ __launch_bounds__(256) void transpose_k(const float* Hs, const float* Cs,
                                                   float* Ho, float* Co) {
    __shared__ float tile[64][129];
    int s = blockIdx.x, jh = blockIdx.y;
    const float* src = blockIdx.z ? Cs : Hs;
    float* dst = blockIdx.z ? Co : Ho;
    #pragma unroll 4
    for (int i = 0; i < 32; ++i) {
        int idx = i * 256 + threadIdx.x;
        int t = idx >> 7, jj = idx & 127;
        tile[t][jj] = src[((size_t)s * 64 + t) * 256 + jh * 128 + jj];
    }
    __syncthreads();
    #pragma unroll 4
    for (int i = 0; i < 32; ++i) {
        int idx = i * 256 + threadIdx.x;
        int jj = idx >> 6, t = idx & 63;
        dst[((size_t)s * 256 + jh * 128 + jj) * 64 + t] = tile[t][jj];
    }
}

// ---------- final: fc3 (64->1) + divide by laneC ----------
__global__ __launch_bounds__(256) void final_k(const short* t2b, const float* fW3, const float* fb3,
                                               const float* laneC, float* out0) {
    int r = blockIdx.x * 256 + threadIdx.x;
    float acc = fb3[0];
    const short* rowp = t2b + (size_t)r * 64;
    #pragma unroll 8
    for (int k = 0; k < 64; ++k) acc += b2f(rowp[k]) * fW3[k];
    out0[r] = acc / laneC[r >> 4];
}

// ---------- host ----------
extern "C" void kernel_launch(void* const* d_in, const int* in_sizes, int n_in,
                              void* d_out, int out_size, void* d_ws, size_t ws_size,
                              hipStream_t stream) {
    (void)in_sizes; (void)n_in; (void)out_size;
    const float* inputData = (const float*)d_in[0];
    const float* lane  = (const float*)d_in[1];
    const float* lgW1  = (const float*)d_in[2];  const float* lgb1 = (const float*)d_in[3];
    const float* lgW2  = (const float*)d_in[4];  const float* lgb2 = (const float*)d_in[5];
    const float* eW1   = (const float*)d_in[6];  const float* eb1  = (const float*)d_in[7];
    const float* eW2   = (const float*)d_in[8];  const float* eb2  = (const float*)d_in[9];
    const float* Wih   = (const float*)d_in[10]; const float* Whh  = (const float*)d_in[11];
    const float* bih   = (const float*)d_in[12]; const float* bhh  = (const float*)d_in[13];
    const float* convw = (const float*)d_in[14]; const float* convb= (const float*)d_in[15];
    const float* oW    = (const float*)d_in[16]; const float* ob   = (const float*)d_in[17];
    const float* fW1   = (const float*)d_in[18]; const float* fb1  = (const float*)d_in[19];
    const float* fW2   = (const float*)d_in[20]; const float* fb2  = (const float*)d_in[21];
    const float* fW3   = (const float*)d_in[22]; const float* fb3  = (const float*)d_in[23];

    float* out0 = (float*)d_out;
    float* Hout = out0 + 65536;
    float* Cout = Hout + (size_t)67108864;

    char* w = (char*)d_ws;
    size_t off = 0;
    auto alloc = [&](size_t bytes) -> void* {
        void* p = w + off;
        off += (bytes + 255) & ~(size_t)255;
        return p;
    };
    float* laneC    = (float*)alloc(4096 * 4);
    float* biasP    = (float*)alloc(1024 * 4);
    short* pW2      = (short*)alloc((size_t)1024 * 384 * 2);
    short* oWp      = (short*)alloc((size_t)128 * 256 * 2);
    short* fW1p     = (short*)alloc((size_t)256 * 128 * 2);
    short* fW2p     = (short*)alloc((size_t)128 * 256 * 2);
    short* eW2p     = (short*)alloc((size_t)128 * 64 * 2);
    short* h1       = (short*)alloc((size_t)64 * 4096 * 64 * 2);
    short* xs       = (short*)alloc((size_t)64 * 4096 * 128 * 2);
    short* predictb = (short*)alloc((size_t)65536 * 256 * 2);
    short* t0b      = (short*)alloc((size_t)65536 * 128 * 2);
    short* t1b      = (short*)alloc((size_t)65536 * 256 * 2);
    short* t2b      = (short*)alloc((size_t)65536 * 64 * 2);
    float* Hstage   = (float*)alloc((size_t)4096 * 64 * 256 * 4);
    float* Cstage   = (float*)alloc((size_t)4096 * 64 * 256 * 4);
    bool staged = ws_size >= off;

    lanec_k<<<16, 256, 0, stream>>>(lane, lgW1, lgb1, lgW2, lgb2, laneC);
    {
        int total = 393216 + 1024 + 32768 + 32768 + 32768 + 8192;
        pack_k<<<(total + 255) / 256, 256, 0, stream>>>(Wih, Whh, bih, bhh, oW, fW1, fW2, eW2,
                                                        pW2, biasP, oWp, fW1p, fW2p, eW2p);
    }
    embed1_k<<<65536, 256, 0, stream>>>(inputData, laneC, eW1, eb1, h1);
    gemm_k<<<dim3(2048, 1), 256, 0, stream>>>(h1, 64, (const short*)nullptr, 0, eW2p, 64,
                                              eb2, (float*)nullptr, xs, 128, 128, 1);

    float* Hd = staged ? Hstage : Hout;
    float* Cd = staged ? Cstage : Cout;
    lstm_k<<<256, 512, 0, stream>>>(xs, pW2, biasP, convw, convb, Hd, Cd, predictb,
                                    staged ? 1 : 0);
    if (staged)
        transpose_k<<<dim3(4096, 2, 2), 256, 0, stream>>>(Hstage, Cstage, Hout, Cout);

    gemm_k<<<dim3(512, 1), 256, 0, stream>>>(predictb, 256, (const short*)nullptr, 0, oWp, 256,
                                             ob, (float*)nullptr, t0b, 128, 128, 0);
    gemm_k<<<dim3(512, 2), 256, 0, stream>>>(t0b, 128, (const short*)nullptr, 0, fW1p, 128,
                                             fb1, (float*)nullptr, t1b, 256, 256, 1);
    gemm_k<<<dim3(512, 1), 256, 0, stream>>>(t1b, 256, (const short*)nullptr, 0, fW2p, 256,
                                             fb2, (float*)nullptr, t2b, 64, 64, 1);
    final_k<<<256, 256, 0, stream>>>(t2b, fW3, fb3, laneC, out0);
}